// Round 21
// baseline (376.367 us; speedup 1.0000x reference)
//
#include <hip/hip_runtime.h>
#include <hip/hip_bf16.h>
#include <cstdint>

#define T_LEN 512
#define B_SZ  256
#define HID   256
#define OUT   128
#define FUSE  384
#define MROWS (T_LEN * B_SZ)   // 131072
#define FT    64               // t-chunk of the fused kernel

typedef _Float16 f16x8 __attribute__((ext_vector_type(8)));
typedef float f32x4 __attribute__((ext_vector_type(4)));

// fp16x2 split of (2^12 * a): a' = h + l*2^-11.  x = (acc_hh + acc_hl*2^-11)*2^-24.
#define PRESC 4096.0f
#define S1    2048.0f
#define S1INV 4.8828125e-4f             // 2^-11
#define C0    5.9604644775390625e-8f    // 2^-24

// V-margin below which a neuron is recomputed with the exact fp32 chain.
#define EPSV  5e-5f

// Raw barriers (no vmcnt drain): private register prefetch loads stay in
// flight across the barrier; only LDS ordering is enforced.
__device__ __forceinline__ void bar_plain() {
  asm volatile("s_barrier" ::: "memory");
}
__device__ __forceinline__ void bar_lds() {
  asm volatile("s_waitcnt lgkmcnt(0)\n\ts_barrier" ::: "memory");
}

// ---------------- prep (merged): W_in fp16x2 images + W_head fp16 ----------
__global__ __launch_bounds__(256) void prep_all(const float* __restrict__ Win,
                                                const float* __restrict__ Wh,
                                                _Float16* __restrict__ Bpack,
                                                _Float16* __restrict__ Wh3)
{
  int gid = blockIdx.x;
  if (gid < 96) {
    int id = gid * 256 + threadIdx.x;          // 24576 = 24 images x 1024 slots
    int img = id >> 10;                        // c*2 + bc
    int c = img >> 1, bc = img & 1;
    int slot = id & 1023;
    int s = slot >> 9, sub = (slot >> 6) & 7, pos = slot & 63;
    int fr = pos & 15, fq = pos >> 4;          // pos = fq*16 + fr
    int n = bc * 128 + sub * 16 + fr;
    int k0 = c * 32 + fq * 8;
    f16x8 v;
#pragma unroll
    for (int j = 0; j < 8; ++j) {
      float w = Win[(size_t)(k0 + j) * HID + n] * PRESC;
      _Float16 h = (_Float16)w;
      v[j] = (s == 0) ? h : (_Float16)((w - (float)h) * S1);
    }
    *reinterpret_cast<f16x8*>(&Bpack[(size_t)img * 8192 + slot * 8]) = v;
  } else {
    int id = (gid - 96) * 256 + threadIdx.x;   // 32768
    int n = id & 127, kk = (id >> 7) & 31, c = id >> 12;
    Wh3[((size_t)c * 128 + n) * 32 + kk] = (_Float16)Wh[(c * 32 + kk) * OUT + n];
  }
}

// ---------------- K12: FUSED GEMM + scan (raw barriers, 4-deep A / 2-deep B)
// Block = (b, h-half). c-loop restructured as 3 groups of 4 chunks with four
// named A prefetch sets (aA..aD) and parity B sets (pbE/pbO): A loads are
// issued FOUR intervals before consumption, B loads TWO — all staying in
// flight across raw barriers. s_setprio(1) wraps the MFMA cluster (waves
// have staggered roles -> scheduler can favor MFMA-entering waves).
// Staging/MFMA arithmetic identical to r12 -> bit-identical output.
__global__ __launch_bounds__(512, 4) void k12_fused(
    const float* __restrict__ vis, const float* __restrict__ imu,
    const float* __restrict__ traj, const _Float16* __restrict__ Bpack,
    const float* __restrict__ bin, const float* __restrict__ wrec,
    uint32_t* __restrict__ sbits, float* __restrict__ scnt)
{
  __shared__ __align__(16) _Float16 Asl[4096];   // [s2][sub4][pos64][j8] 8KB
  __shared__ float xt[FT][130];                  // 33.3KB; 2 lanes/bank (free)

  const int bid = blockIdx.x;
  const int b   = bid & 255;
  const int hh  = bid >> 8;                 // h-half 0/1
  const int tid = threadIdx.x;
  const int wid = tid >> 6, lane = tid & 63;
  const int wr = wid >> 2, wc = wid & 3;    // 2M(t) x 4N(h)
  const int fr = lane & 15, fq = lane >> 4;

  // A staging coords (threads 0..255 stage 8 floats = one j8 slot each)
  const int arow = tid >> 2;                // 0..63 (tid<256)
  const int ak   = (tid & 3) * 8;           // k-offset {0,8,16,24}
  const int asub = arow >> 4;
  const int apos = (tid & 3) * 16 + (arow & 15);   // pos = fq*16+fr

  // scan state (threads 0..127: h_local = tid)
  float V = 0.f, S = 0.f, cnt = 0.f, minm = 1e9f;
  const float wrv = (tid < 128) ? wrec[hh * 128 + tid] : 0.f;
  float bvv[2];
  bvv[0] = bin[hh * 128 + wc * 32 + fr];
  bvv[1] = bin[hh * 128 + wc * 32 + 16 + fr];

  float4 aA0, aA1, aB0, aB1, aC0, aC1, aD0, aD1;   // 4 named A prefetch sets
  f16x8 pbE0, pbE1, pbE2, pbE3;                    // B even-parity set
  f16x8 pbO0, pbO1, pbO2, pbO3;                    // B odd-parity set

  auto loadA = [&](int cc, float4& d0, float4& d1) {   // cc = linear chunk
    if (tid < 256 && cc < 96) {
      int tcc = cc / 12, c = cc - tcc * 12;
      size_t m = (size_t)(tcc * FT + arow) * B_SZ + b;
      const float* src; size_t off;
      if (c < 8)       { src = vis;  off = m * 256 + c * 32 + ak; }
      else if (c < 10) { src = imu;  off = m * 64 + (c - 8) * 32 + ak; }
      else             { src = traj; off = m * 64 + (c - 10) * 32 + ak; }
      d0 = *reinterpret_cast<const float4*>(src + off);
      d1 = *reinterpret_cast<const float4*>(src + off + 4);
    }
  };
  auto loadB = [&](int cc, f16x8& d0, f16x8& d1, f16x8& d2, f16x8& d3) {
    if (cc < 96) {
      int c = cc - (cc / 12) * 12;
      const _Float16* base = Bpack + (size_t)(c * 2 + hh) * 8192;
      d0 = *reinterpret_cast<const f16x8*>(base + (wc * 2 + 0) * 512 + lane * 8);
      d1 = *reinterpret_cast<const f16x8*>(base + (wc * 2 + 1) * 512 + lane * 8);
      d2 = *reinterpret_cast<const f16x8*>(base + 4096 + (wc * 2 + 0) * 512 + lane * 8);
      d3 = *reinterpret_cast<const f16x8*>(base + 4096 + (wc * 2 + 1) * 512 + lane * 8);
    }
  };

  auto stage = [&](const float4& s0, const float4& s1) {
    if (tid < 256) {
      float av[8] = {s0.x, s0.y, s0.z, s0.w, s1.x, s1.y, s1.z, s1.w};
      f16x8 vh, vl;
#pragma unroll
      for (int j = 0; j < 8; ++j) {
        float w = av[j] * PRESC;
        _Float16 h = (_Float16)w;
        vh[j] = h;
        vl[j] = (_Float16)((w - (float)h) * S1);
      }
      *reinterpret_cast<f16x8*>(&Asl[asub * 512 + apos * 8])        = vh;
      *reinterpret_cast<f16x8*>(&Asl[2048 + asub * 512 + apos * 8]) = vl;
    }
  };

  f32x4 acc0[2][2];
  f32x4 acc1[2][2];

  auto mma = [&](f16x8 bh_0, f16x8 bh_1, f16x8 bl_0, f16x8 bl_1) {
    __builtin_amdgcn_s_setprio(1);
#pragma unroll
    for (int mf = 0; mf < 2; ++mf) {
      int sa = wr * 2 + mf;
      f16x8 ah = *reinterpret_cast<const f16x8*>(&Asl[sa * 512 + lane * 8]);
      f16x8 al = *reinterpret_cast<const f16x8*>(&Asl[2048 + sa * 512 + lane * 8]);
      acc0[mf][0] = __builtin_amdgcn_mfma_f32_16x16x32_f16(ah, bh_0, acc0[mf][0], 0, 0, 0);
      acc1[mf][0] = __builtin_amdgcn_mfma_f32_16x16x32_f16(ah, bl_0, acc1[mf][0], 0, 0, 0);
      acc1[mf][0] = __builtin_amdgcn_mfma_f32_16x16x32_f16(al, bh_0, acc1[mf][0], 0, 0, 0);
      acc0[mf][1] = __builtin_amdgcn_mfma_f32_16x16x32_f16(ah, bh_1, acc0[mf][1], 0, 0, 0);
      acc1[mf][1] = __builtin_amdgcn_mfma_f32_16x16x32_f16(ah, bl_1, acc1[mf][1], 0, 0, 0);
      acc1[mf][1] = __builtin_amdgcn_mfma_f32_16x16x32_f16(al, bh_1, acc1[mf][1], 0, 0, 0);
    }
    __builtin_amdgcn_s_setprio(0);
  };

  // prologue: A 4-deep, B 2-deep
  loadA(0, aA0, aA1);
  loadA(1, aB0, aB1);
  loadA(2, aC0, aC1);
  loadA(3, aD0, aD1);
  loadB(0, pbE0, pbE1, pbE2, pbE3);
  loadB(1, pbO0, pbO1, pbO2, pbO3);

#define CHUNK(S0, S1, P0, P1, P2, P3, CC)                                     \
  {                                                                           \
    bar_plain();            /* Asl free: reads already in regs */             \
    stage(S0, S1);                                                            \
    loadA((CC) + 4, S0, S1);            /* 4-deep reissue */                  \
    bar_lds();              /* ds_writes visible */                           \
    f16x8 t0 = P0, t1 = P1, t2 = P2, t3 = P3;                                 \
    loadB((CC) + 2, P0, P1, P2, P3);    /* 2-deep reissue */                  \
    mma(t0, t1, t2, t3);                                                      \
  }

  for (int tc = 0; tc < 8; ++tc) {
#pragma unroll
    for (int mf = 0; mf < 2; ++mf)
#pragma unroll
      for (int nf = 0; nf < 2; ++nf) {
        acc0[mf][nf] = (f32x4){0.f, 0.f, 0.f, 0.f};
        acc1[mf][nf] = (f32x4){0.f, 0.f, 0.f, 0.f};
      }

#pragma unroll 1
    for (int i = 0; i < 3; ++i) {
      const int cc0 = tc * 12 + 4 * i;
      CHUNK(aA0, aA1, pbE0, pbE1, pbE2, pbE3, cc0 + 0)
      CHUNK(aB0, aB1, pbO0, pbO1, pbO2, pbO3, cc0 + 1)
      CHUNK(aC0, aC1, pbE0, pbE1, pbE2, pbE3, cc0 + 2)
      CHUNK(aD0, aD1, pbO0, pbO1, pbO2, pbO3, cc0 + 3)
    }

    // epilogue: x-tile to LDS (full __syncthreads handoffs; 2 per tc only)
    __syncthreads();
#pragma unroll
    for (int mf = 0; mf < 2; ++mf)
#pragma unroll
      for (int nf = 0; nf < 2; ++nf) {
        int col = wc * 32 + nf * 16 + fr;
        int rbase = wr * 32 + mf * 16 + fq * 4;
#pragma unroll
        for (int r = 0; r < 4; ++r)
          xt[rbase + r][col] =
              (acc0[mf][nf][r] + acc1[mf][nf][r] * S1INV) * C0 + bvv[nf];
      }
    __syncthreads();                       // x-tile ready for scan

    // scan: threads 0..127 (waves 0,1), arithmetic = proven k2_scan verbatim
    if (tid < 128) {
#pragma unroll 1
      for (int u0 = 0; u0 < FT; u0 += 8) {
        float xv[8];
#pragma unroll
        for (int u = 0; u < 8; ++u) xv[u] = xt[u0 + u][tid];
#pragma unroll
        for (int u = 0; u < 8; ++u) {
          V = 0.9f * V + xv[u] + wrv * S;
          float d = V - 1.0f;
          float sn = (d > 0.0f) ? 1.0f : 0.0f;
          minm = fminf(minm, fabsf(d));
          V -= sn;
          cnt += sn;
          S = sn;
          unsigned long long mk = __ballot(sn > 0.5f);
          if (lane == 0) {
            int m = (tc * FT + u0 + u) * B_SZ + b;
            int wv = hh * 2 + wid;
            sbits[(size_t)m * 8 + wv * 2 + 0] = (uint32_t)(mk & 0xffffffffull);
            sbits[(size_t)m * 8 + wv * 2 + 1] = (uint32_t)(mk >> 32);
          }
        }
      }
    }
    // next tc's first bar_plain orders scan xt-reads vs. future xt writes
  }

  if (tid < 128)
    scnt[b * HID + hh * 128 + tid] = (minm < EPSV) ? (-cnt - 1.0f) : cnt;
}
#undef CHUNK

// ---------------- K2_fix: 512 thr, 1 t/thread, FSL=12, 4-deep prefetch -----
#define FSL 12
__global__ __launch_bounds__(512) void k2_fix(
    const float* __restrict__ vis, const float* __restrict__ imu,
    const float* __restrict__ traj, const float* __restrict__ Win,
    const float* __restrict__ bin, const float* __restrict__ wrec,
    uint32_t* __restrict__ sbits, float* __restrict__ scnt)
{
  __shared__ __align__(16) float Wlds[FSL][392];   // 16B-aligned rows
  __shared__ float xcol[FSL][521];
  __shared__ unsigned char spkb[FSL][516];
  __shared__ int dlist[256];
  __shared__ int nd;

  const int b = blockIdx.x;
  const int tid = threadIdx.x;
  if (tid == 0) nd = 0;
  __syncthreads();
  if (tid < 256) {
    if (scnt[b * HID + tid] < -0.5f) {
      int p = atomicAdd(&nd, 1);
      dlist[p] = tid;
    }
  }
  __syncthreads();
  const int nd0 = nd;
  if (nd0 == 0) return;

  const int t = tid;
  const size_t r = (size_t)t * B_SZ + b;

  for (int sb = 0; sb < nd0; sb += FSL) {
    const int nsb = min(FSL, nd0 - sb);

    for (int idx = tid; idx < FSL * 384; idx += 512) {
      int s = idx / 384, k = idx - s * 384;
      float w = 0.f;
      if (s < nsb) w = Win[(size_t)k * HID + dlist[sb + s]];
      Wlds[s][k] = w;
    }
    __syncthreads();

    float x[FSL];
#pragma unroll
    for (int s = 0; s < FSL; ++s) x[s] = 0.f;

#define SEG(SRC, LEN, DIM, WOFS)                                              \
    {                                                                         \
      const float* src = SRC + r * DIM;                                       \
      _Pragma("unroll 1")                                                     \
      for (int q = 0; q < LEN; q += 4) {                                      \
        float4 a0 = *reinterpret_cast<const float4*>(src + q * 4);            \
        float4 a1 = *reinterpret_cast<const float4*>(src + q * 4 + 4);        \
        float4 a2 = *reinterpret_cast<const float4*>(src + q * 4 + 8);        \
        float4 a3 = *reinterpret_cast<const float4*>(src + q * 4 + 12);       \
        _Pragma("unroll")                                                     \
        for (int s = 0; s < FSL; ++s) {                                       \
          float4 w = *reinterpret_cast<const float4*>(&Wlds[s][WOFS + q * 4]);\
          x[s] += a0.x * w.x; x[s] += a0.y * w.y;                             \
          x[s] += a0.z * w.z; x[s] += a0.w * w.w;                             \
        }                                                                     \
        _Pragma("unroll")                                                     \
        for (int s = 0; s < FSL; ++s) {                                       \
          float4 w = *reinterpret_cast<const float4*>(&Wlds[s][WOFS + q * 4 + 4]); \
          x[s] += a1.x * w.x; x[s] += a1.y * w.y;                             \
          x[s] += a1.z * w.z; x[s] += a1.w * w.w;                             \
        }                                                                     \
        _Pragma("unroll")                                                     \
        for (int s = 0; s < FSL; ++s) {                                       \
          float4 w = *reinterpret_cast<const float4*>(&Wlds[s][WOFS + q * 4 + 8]); \
          x[s] += a2.x * w.x; x[s] += a2.y * w.y;                             \
          x[s] += a2.z * w.z; x[s] += a2.w * w.w;                             \
        }                                                                     \
        _Pragma("unroll")                                                     \
        for (int s = 0; s < FSL; ++s) {                                       \
          float4 w = *reinterpret_cast<const float4*>(&Wlds[s][WOFS + q * 4 + 12]); \
          x[s] += a3.x * w.x; x[s] += a3.y * w.y;                             \
          x[s] += a3.z * w.z; x[s] += a3.w * w.w;                             \
        }                                                                     \
      }                                                                       \
    }

    SEG(vis,  64, 256, 0)
    SEG(imu,  16, 64,  256)
    SEG(traj, 16, 64,  320)
#undef SEG

#pragma unroll
    for (int s = 0; s < FSL; ++s) {
      if (s < nsb) xcol[s][t] = x[s] + bin[dlist[sb + s]];
    }
    __syncthreads();

    if (tid < nsb) {
      const int h = dlist[sb + tid];
      const float mywr = wrec[h];
      float V = 0.f, Sv = 0.f, cnt = 0.f;
#pragma unroll 1
      for (int tt = 0; tt < T_LEN; ++tt) {
        float xv = xcol[tid][tt];
        V = 0.9f * V + xv + mywr * Sv;
        float sn = (V - 1.0f > 0.0f) ? 1.0f : 0.0f;
        V -= sn;
        cnt += sn;
        Sv = sn;
        spkb[tid][tt] = (unsigned char)sn;
      }
      scnt[b * HID + h] = cnt;
    }
    __syncthreads();

    for (int p = tid; p < T_LEN * 8; p += 512) {
      int tt = p >> 3, wv = p & 7;
      uint32_t mc = 0, ms = 0;
      for (int j = 0; j < nsb; ++j) {
        int h = dlist[sb + j];
        if ((h >> 5) == wv) {
          uint32_t bit = 1u << (h & 31);
          mc |= bit;
          if (spkb[j][tt]) ms |= bit;
        }
      }
      if (mc) {
        size_t w = ((size_t)tt * B_SZ + b) * 8 + wv;
        sbits[w] = (sbits[w] & ~mc) | ms;
      }
    }
    __syncthreads();
  }
}

// ---------------- K3: logits = spikes @ W_head + b_head (r12-proven) -------
#define LDA 40
__global__ __launch_bounds__(256) void k3_logits(
    const uint32_t* __restrict__ sbits, const _Float16* __restrict__ Wh3,
    const float* __restrict__ bhead, float* __restrict__ logits)
{
  __shared__ __align__(16) _Float16 Sa[128][LDA];
  __shared__ __align__(16) _Float16 Wt[128][LDA];

  const int tid  = threadIdx.x;
  const int brow = blockIdx.x * 128;
  const int srow = tid >> 1, sks = (tid & 1) << 4;
  const int wid = tid >> 6, lane = tid & 63;
  const int wr = wid >> 1, wc = wid & 1;
  const int fr = lane & 15, fq = lane >> 4;

  f32x4 acc[4][4] = {};
  uint32_t wbits;
  uint4 wb0, wb1;

  auto loadS = [&](int c) { wbits = sbits[(size_t)(brow + srow) * 8 + c]; };
  auto loadW = [&](int c) {
    const _Float16* p = Wh3 + ((size_t)c * 128 + srow) * 32 + sks;
    wb0 = *reinterpret_cast<const uint4*>(p);
    wb1 = *reinterpret_cast<const uint4*>(p + 8);
  };

  loadS(0); loadW(0);

  for (int c = 0; c < 8; ++c) {
    __syncthreads();
    {
      f16x8 e0, e1;
#pragma unroll
      for (int j = 0; j < 8; ++j) {
        e0[j] = (_Float16)(float)((wbits >> (sks + j)) & 1u);
        e1[j] = (_Float16)(float)((wbits >> (sks + 8 + j)) & 1u);
      }
      *reinterpret_cast<f16x8*>(&Sa[srow][sks])     = e0;
      *reinterpret_cast<f16x8*>(&Sa[srow][sks + 8]) = e1;
    }
    *reinterpret_cast<uint4*>(&Wt[srow][sks])     = wb0;
    *reinterpret_cast<uint4*>(&Wt[srow][sks + 8]) = wb1;
    __syncthreads();
    if (c + 1 < 8) { loadS(c + 1); loadW(c + 1); }

    f16x8 wf[4];
#pragma unroll
    for (int nf = 0; nf < 4; ++nf)
      wf[nf] = *reinterpret_cast<const f16x8*>(&Wt[wc * 64 + nf * 16 + fr][fq * 8]);
#pragma unroll
    for (int mf = 0; mf < 4; ++mf) {
      f16x8 sf = *reinterpret_cast<const f16x8*>(&Sa[wr * 64 + mf * 16 + fr][fq * 8]);
#pragma unroll
      for (int nf = 0; nf < 4; ++nf)
        acc[mf][nf] = __builtin_amdgcn_mfma_f32_16x16x32_f16(sf, wf[nf], acc[mf][nf], 0, 0, 0);
    }
  }

#pragma unroll
  for (int mf = 0; mf < 4; ++mf)
#pragma unroll
    for (int nf = 0; nf < 4; ++nf) {
      int n = wc * 64 + nf * 16 + fr;
      float bv = bhead[n];
#pragma unroll
      for (int r = 0; r < 4; ++r) {
        int m = brow + wr * 64 + mf * 16 + fq * 4 + r;
        logits[(size_t)m * OUT + n] = acc[mf][nf][r] + bv;
      }
    }
}

// ---------------- K4: out = (spike_counts / T) @ W_head + b_head (fp32) ----
__global__ __launch_bounds__(128) void k4_out(
    const float* __restrict__ scnt, const float* __restrict__ Whead,
    const float* __restrict__ bhead, float* __restrict__ outp)
{
  __shared__ float s[HID];
  const int b = blockIdx.x;
  const int o = threadIdx.x;
  s[o] = scnt[b * HID + o];
  s[o + 128] = scnt[b * HID + o + 128];
  __syncthreads();
  float acc = 0.f;
#pragma unroll 8
  for (int h = 0; h < HID; ++h) acc += s[h] * Whead[h * OUT + o];
  outp[b * OUT + o] = acc * (1.0f / (float)T_LEN) + bhead[o];
}

extern "C" void kernel_launch(void* const* d_in, const int* in_sizes, int n_in,
                              void* d_out, int out_size, void* d_ws, size_t ws_size,
                              hipStream_t stream)
{
  const float* vis   = (const float*)d_in[0];
  const float* imu   = (const float*)d_in[1];
  const float* traj  = (const float*)d_in[2];
  const float* Win   = (const float*)d_in[3];
  const float* bin   = (const float*)d_in[4];
  const float* wrec  = (const float*)d_in[5];
  const float* Whead = (const float*)d_in[6];
  const float* bhead = (const float*)d_in[7];

  float* outp   = (float*)d_out;           // [B, OUT] (return order: out, logits)
  float* logits = outp + B_SZ * OUT;       // [T, B, OUT]

  char* ws = (char*)d_ws;
  const size_t SBITS_B = (size_t)MROWS * 8 * 4;        // 4.19 MB
  const size_t SCNT_B  = (size_t)B_SZ * HID * 4;       // 256 KB
  const size_t BPACK_B = (size_t)24 * 8192 * 2;        // 384 KB
  uint32_t* sbits = (uint32_t*)ws;
  float*    scnt  = (float*)(ws + SBITS_B);
  _Float16* Bpack = (_Float16*)(ws + SBITS_B + SCNT_B);
  _Float16* Wh3   = (_Float16*)(ws + SBITS_B + SCNT_B + BPACK_B);

  prep_all  <<<dim3(224),         256, 0, stream>>>(Win, Whead, Bpack, Wh3);
  k12_fused <<<dim3(512),         512, 0, stream>>>(vis, imu, traj, Bpack, bin,
                                                    wrec, sbits, scnt);
  k2_fix    <<<dim3(B_SZ),        512, 0, stream>>>(vis, imu, traj, Win, bin,
                                                    wrec, sbits, scnt);
  k3_logits <<<dim3(MROWS / 128), 256, 0, stream>>>(sbits, Wh3, bhead, logits);
  k4_out    <<<dim3(B_SZ),        128, 0, stream>>>(scnt, Whead, bhead, outp);
}

// Round 22
// 318.035 us; speedup vs baseline: 1.1834x; 1.1834x over previous
//
#include <hip/hip_runtime.h>
#include <hip/hip_bf16.h>
#include <cstdint>

#define T_LEN 512
#define B_SZ  256
#define HID   256
#define OUT   128
#define FUSE  384
#define MROWS (T_LEN * B_SZ)   // 131072
#define FT    64               // t-chunk of the fused kernel

typedef _Float16 f16x8 __attribute__((ext_vector_type(8)));
typedef float f32x4 __attribute__((ext_vector_type(4)));

// fp16x2 split of (2^12 * a): a' = h + l*2^-11.  x = (acc_hh + acc_hl*2^-11)*2^-24.
#define PRESC 4096.0f
#define S1    2048.0f
#define S1INV 4.8828125e-4f             // 2^-11
#define C0    5.9604644775390625e-8f    // 2^-24

// V-margin below which a neuron is recomputed with the exact fp32 chain.
#define EPSV  5e-5f

// Raw barriers (no vmcnt drain): private register prefetch loads stay in
// flight across the barrier; only LDS ordering is enforced.
__device__ __forceinline__ void bar_plain() {
  asm volatile("s_barrier" ::: "memory");
}
__device__ __forceinline__ void bar_lds() {
  asm volatile("s_waitcnt lgkmcnt(0)\n\ts_barrier" ::: "memory");
}

// ---------------- prep (merged): W_in fp16x2 images + W_head fp16 ----------
__global__ __launch_bounds__(256) void prep_all(const float* __restrict__ Win,
                                                const float* __restrict__ Wh,
                                                _Float16* __restrict__ Bpack,
                                                _Float16* __restrict__ Wh3)
{
  int gid = blockIdx.x;
  if (gid < 96) {
    int id = gid * 256 + threadIdx.x;          // 24576 = 24 images x 1024 slots
    int img = id >> 10;                        // c*2 + bc
    int c = img >> 1, bc = img & 1;
    int slot = id & 1023;
    int s = slot >> 9, sub = (slot >> 6) & 7, pos = slot & 63;
    int fr = pos & 15, fq = pos >> 4;          // pos = fq*16 + fr
    int n = bc * 128 + sub * 16 + fr;
    int k0 = c * 32 + fq * 8;
    f16x8 v;
#pragma unroll
    for (int j = 0; j < 8; ++j) {
      float w = Win[(size_t)(k0 + j) * HID + n] * PRESC;
      _Float16 h = (_Float16)w;
      v[j] = (s == 0) ? h : (_Float16)((w - (float)h) * S1);
    }
    *reinterpret_cast<f16x8*>(&Bpack[(size_t)img * 8192 + slot * 8]) = v;
  } else {
    int id = (gid - 96) * 256 + threadIdx.x;   // 32768
    int n = id & 127, kk = (id >> 7) & 31, c = id >> 12;
    Wh3[((size_t)c * 128 + n) * 32 + kk] = (_Float16)Wh[(c * 32 + kk) * OUT + n];
  }
}

// ---------------- K12: FUSED GEMM + scan (raw barriers, 4-deep A / 2-deep B)
// launch_bounds (512,2): VGPR cap 128 (was 64 at (512,4) -> r21 spilled).
// At ~96-120 VGPR the pool still admits 4 waves/SIMD => same 2 blocks/CU as
// r12-r20, now without scratch. Schedule identical to r21; arithmetic
// identical to r12 -> bit-identical output.
__global__ __launch_bounds__(512, 2) void k12_fused(
    const float* __restrict__ vis, const float* __restrict__ imu,
    const float* __restrict__ traj, const _Float16* __restrict__ Bpack,
    const float* __restrict__ bin, const float* __restrict__ wrec,
    uint32_t* __restrict__ sbits, float* __restrict__ scnt)
{
  __shared__ __align__(16) _Float16 Asl[4096];   // [s2][sub4][pos64][j8] 8KB
  __shared__ float xt[FT][130];                  // 33.3KB; 2 lanes/bank (free)

  const int bid = blockIdx.x;
  const int b   = bid & 255;
  const int hh  = bid >> 8;                 // h-half 0/1
  const int tid = threadIdx.x;
  const int wid = tid >> 6, lane = tid & 63;
  const int wr = wid >> 2, wc = wid & 3;    // 2M(t) x 4N(h)
  const int fr = lane & 15, fq = lane >> 4;

  // A staging coords (threads 0..255 stage 8 floats = one j8 slot each)
  const int arow = tid >> 2;                // 0..63 (tid<256)
  const int ak   = (tid & 3) * 8;           // k-offset {0,8,16,24}
  const int asub = arow >> 4;
  const int apos = (tid & 3) * 16 + (arow & 15);   // pos = fq*16+fr

  // scan state (threads 0..127: h_local = tid)
  float V = 0.f, S = 0.f, cnt = 0.f, minm = 1e9f;
  const float wrv = (tid < 128) ? wrec[hh * 128 + tid] : 0.f;
  float bvv[2];
  bvv[0] = bin[hh * 128 + wc * 32 + fr];
  bvv[1] = bin[hh * 128 + wc * 32 + 16 + fr];

  float4 aA0, aA1, aB0, aB1, aC0, aC1, aD0, aD1;   // 4 named A prefetch sets
  f16x8 pbE0, pbE1, pbE2, pbE3;                    // B even-parity set
  f16x8 pbO0, pbO1, pbO2, pbO3;                    // B odd-parity set

  auto loadA = [&](int cc, float4& d0, float4& d1) {   // cc = linear chunk
    if (tid < 256 && cc < 96) {
      int tcc = cc / 12, c = cc - tcc * 12;
      size_t m = (size_t)(tcc * FT + arow) * B_SZ + b;
      const float* src; size_t off;
      if (c < 8)       { src = vis;  off = m * 256 + c * 32 + ak; }
      else if (c < 10) { src = imu;  off = m * 64 + (c - 8) * 32 + ak; }
      else             { src = traj; off = m * 64 + (c - 10) * 32 + ak; }
      d0 = *reinterpret_cast<const float4*>(src + off);
      d1 = *reinterpret_cast<const float4*>(src + off + 4);
    }
  };
  auto loadB = [&](int cc, f16x8& d0, f16x8& d1, f16x8& d2, f16x8& d3) {
    if (cc < 96) {
      int c = cc - (cc / 12) * 12;
      const _Float16* base = Bpack + (size_t)(c * 2 + hh) * 8192;
      d0 = *reinterpret_cast<const f16x8*>(base + (wc * 2 + 0) * 512 + lane * 8);
      d1 = *reinterpret_cast<const f16x8*>(base + (wc * 2 + 1) * 512 + lane * 8);
      d2 = *reinterpret_cast<const f16x8*>(base + 4096 + (wc * 2 + 0) * 512 + lane * 8);
      d3 = *reinterpret_cast<const f16x8*>(base + 4096 + (wc * 2 + 1) * 512 + lane * 8);
    }
  };

  auto stage = [&](const float4& s0, const float4& s1) {
    if (tid < 256) {
      float av[8] = {s0.x, s0.y, s0.z, s0.w, s1.x, s1.y, s1.z, s1.w};
      f16x8 vh, vl;
#pragma unroll
      for (int j = 0; j < 8; ++j) {
        float w = av[j] * PRESC;
        _Float16 h = (_Float16)w;
        vh[j] = h;
        vl[j] = (_Float16)((w - (float)h) * S1);
      }
      *reinterpret_cast<f16x8*>(&Asl[asub * 512 + apos * 8])        = vh;
      *reinterpret_cast<f16x8*>(&Asl[2048 + asub * 512 + apos * 8]) = vl;
    }
  };

  f32x4 acc0[2][2];
  f32x4 acc1[2][2];

  auto mma = [&](f16x8 bh_0, f16x8 bh_1, f16x8 bl_0, f16x8 bl_1) {
    __builtin_amdgcn_s_setprio(1);
#pragma unroll
    for (int mf = 0; mf < 2; ++mf) {
      int sa = wr * 2 + mf;
      f16x8 ah = *reinterpret_cast<const f16x8*>(&Asl[sa * 512 + lane * 8]);
      f16x8 al = *reinterpret_cast<const f16x8*>(&Asl[2048 + sa * 512 + lane * 8]);
      acc0[mf][0] = __builtin_amdgcn_mfma_f32_16x16x32_f16(ah, bh_0, acc0[mf][0], 0, 0, 0);
      acc1[mf][0] = __builtin_amdgcn_mfma_f32_16x16x32_f16(ah, bl_0, acc1[mf][0], 0, 0, 0);
      acc1[mf][0] = __builtin_amdgcn_mfma_f32_16x16x32_f16(al, bh_0, acc1[mf][0], 0, 0, 0);
      acc0[mf][1] = __builtin_amdgcn_mfma_f32_16x16x32_f16(ah, bh_1, acc0[mf][1], 0, 0, 0);
      acc1[mf][1] = __builtin_amdgcn_mfma_f32_16x16x32_f16(ah, bl_1, acc1[mf][1], 0, 0, 0);
      acc1[mf][1] = __builtin_amdgcn_mfma_f32_16x16x32_f16(al, bh_1, acc1[mf][1], 0, 0, 0);
    }
    __builtin_amdgcn_s_setprio(0);
  };

  // prologue: A 4-deep, B 2-deep
  loadA(0, aA0, aA1);
  loadA(1, aB0, aB1);
  loadA(2, aC0, aC1);
  loadA(3, aD0, aD1);
  loadB(0, pbE0, pbE1, pbE2, pbE3);
  loadB(1, pbO0, pbO1, pbO2, pbO3);

#define CHUNK(S0, S1, P0, P1, P2, P3, CC)                                     \
  {                                                                           \
    bar_plain();            /* Asl free: reads already in regs */             \
    stage(S0, S1);                                                            \
    loadA((CC) + 4, S0, S1);            /* 4-deep reissue */                  \
    bar_lds();              /* ds_writes visible */                           \
    f16x8 t0 = P0, t1 = P1, t2 = P2, t3 = P3;                                 \
    loadB((CC) + 2, P0, P1, P2, P3);    /* 2-deep reissue */                  \
    mma(t0, t1, t2, t3);                                                      \
  }

  for (int tc = 0; tc < 8; ++tc) {
#pragma unroll
    for (int mf = 0; mf < 2; ++mf)
#pragma unroll
      for (int nf = 0; nf < 2; ++nf) {
        acc0[mf][nf] = (f32x4){0.f, 0.f, 0.f, 0.f};
        acc1[mf][nf] = (f32x4){0.f, 0.f, 0.f, 0.f};
      }

#pragma unroll 1
    for (int i = 0; i < 3; ++i) {
      const int cc0 = tc * 12 + 4 * i;
      CHUNK(aA0, aA1, pbE0, pbE1, pbE2, pbE3, cc0 + 0)
      CHUNK(aB0, aB1, pbO0, pbO1, pbO2, pbO3, cc0 + 1)
      CHUNK(aC0, aC1, pbE0, pbE1, pbE2, pbE3, cc0 + 2)
      CHUNK(aD0, aD1, pbO0, pbO1, pbO2, pbO3, cc0 + 3)
    }

    // epilogue: x-tile to LDS (full __syncthreads handoffs; 2 per tc only)
    __syncthreads();
#pragma unroll
    for (int mf = 0; mf < 2; ++mf)
#pragma unroll
      for (int nf = 0; nf < 2; ++nf) {
        int col = wc * 32 + nf * 16 + fr;
        int rbase = wr * 32 + mf * 16 + fq * 4;
#pragma unroll
        for (int r = 0; r < 4; ++r)
          xt[rbase + r][col] =
              (acc0[mf][nf][r] + acc1[mf][nf][r] * S1INV) * C0 + bvv[nf];
      }
    __syncthreads();                       // x-tile ready for scan

    // scan: threads 0..127 (waves 0,1), arithmetic = proven k2_scan verbatim
    if (tid < 128) {
#pragma unroll 1
      for (int u0 = 0; u0 < FT; u0 += 8) {
        float xv[8];
#pragma unroll
        for (int u = 0; u < 8; ++u) xv[u] = xt[u0 + u][tid];
#pragma unroll
        for (int u = 0; u < 8; ++u) {
          V = 0.9f * V + xv[u] + wrv * S;
          float d = V - 1.0f;
          float sn = (d > 0.0f) ? 1.0f : 0.0f;
          minm = fminf(minm, fabsf(d));
          V -= sn;
          cnt += sn;
          S = sn;
          unsigned long long mk = __ballot(sn > 0.5f);
          if (lane == 0) {
            int m = (tc * FT + u0 + u) * B_SZ + b;
            int wv = hh * 2 + wid;
            sbits[(size_t)m * 8 + wv * 2 + 0] = (uint32_t)(mk & 0xffffffffull);
            sbits[(size_t)m * 8 + wv * 2 + 1] = (uint32_t)(mk >> 32);
          }
        }
      }
    }
    // next tc's first bar_plain orders scan xt-reads vs. future xt writes
  }

  if (tid < 128)
    scnt[b * HID + hh * 128 + tid] = (minm < EPSV) ? (-cnt - 1.0f) : cnt;
}
#undef CHUNK

// ---------------- K2_fix: 512 thr, 1 t/thread, FSL=12, 4-deep prefetch -----
#define FSL 12
__global__ __launch_bounds__(512) void k2_fix(
    const float* __restrict__ vis, const float* __restrict__ imu,
    const float* __restrict__ traj, const float* __restrict__ Win,
    const float* __restrict__ bin, const float* __restrict__ wrec,
    uint32_t* __restrict__ sbits, float* __restrict__ scnt)
{
  __shared__ __align__(16) float Wlds[FSL][392];   // 16B-aligned rows
  __shared__ float xcol[FSL][521];
  __shared__ unsigned char spkb[FSL][516];
  __shared__ int dlist[256];
  __shared__ int nd;

  const int b = blockIdx.x;
  const int tid = threadIdx.x;
  if (tid == 0) nd = 0;
  __syncthreads();
  if (tid < 256) {
    if (scnt[b * HID + tid] < -0.5f) {
      int p = atomicAdd(&nd, 1);
      dlist[p] = tid;
    }
  }
  __syncthreads();
  const int nd0 = nd;
  if (nd0 == 0) return;

  const int t = tid;
  const size_t r = (size_t)t * B_SZ + b;

  for (int sb = 0; sb < nd0; sb += FSL) {
    const int nsb = min(FSL, nd0 - sb);

    for (int idx = tid; idx < FSL * 384; idx += 512) {
      int s = idx / 384, k = idx - s * 384;
      float w = 0.f;
      if (s < nsb) w = Win[(size_t)k * HID + dlist[sb + s]];
      Wlds[s][k] = w;
    }
    __syncthreads();

    float x[FSL];
#pragma unroll
    for (int s = 0; s < FSL; ++s) x[s] = 0.f;

#define SEG(SRC, LEN, DIM, WOFS)                                              \
    {                                                                         \
      const float* src = SRC + r * DIM;                                       \
      _Pragma("unroll 1")                                                     \
      for (int q = 0; q < LEN; q += 4) {                                      \
        float4 a0 = *reinterpret_cast<const float4*>(src + q * 4);            \
        float4 a1 = *reinterpret_cast<const float4*>(src + q * 4 + 4);        \
        float4 a2 = *reinterpret_cast<const float4*>(src + q * 4 + 8);        \
        float4 a3 = *reinterpret_cast<const float4*>(src + q * 4 + 12);       \
        _Pragma("unroll")                                                     \
        for (int s = 0; s < FSL; ++s) {                                       \
          float4 w = *reinterpret_cast<const float4*>(&Wlds[s][WOFS + q * 4]);\
          x[s] += a0.x * w.x; x[s] += a0.y * w.y;                             \
          x[s] += a0.z * w.z; x[s] += a0.w * w.w;                             \
        }                                                                     \
        _Pragma("unroll")                                                     \
        for (int s = 0; s < FSL; ++s) {                                       \
          float4 w = *reinterpret_cast<const float4*>(&Wlds[s][WOFS + q * 4 + 4]); \
          x[s] += a1.x * w.x; x[s] += a1.y * w.y;                             \
          x[s] += a1.z * w.z; x[s] += a1.w * w.w;                             \
        }                                                                     \
        _Pragma("unroll")                                                     \
        for (int s = 0; s < FSL; ++s) {                                       \
          float4 w = *reinterpret_cast<const float4*>(&Wlds[s][WOFS + q * 4 + 8]); \
          x[s] += a2.x * w.x; x[s] += a2.y * w.y;                             \
          x[s] += a2.z * w.z; x[s] += a2.w * w.w;                             \
        }                                                                     \
        _Pragma("unroll")                                                     \
        for (int s = 0; s < FSL; ++s) {                                       \
          float4 w = *reinterpret_cast<const float4*>(&Wlds[s][WOFS + q * 4 + 12]); \
          x[s] += a3.x * w.x; x[s] += a3.y * w.y;                             \
          x[s] += a3.z * w.z; x[s] += a3.w * w.w;                             \
        }                                                                     \
      }                                                                       \
    }

    SEG(vis,  64, 256, 0)
    SEG(imu,  16, 64,  256)
    SEG(traj, 16, 64,  320)
#undef SEG

#pragma unroll
    for (int s = 0; s < FSL; ++s) {
      if (s < nsb) xcol[s][t] = x[s] + bin[dlist[sb + s]];
    }
    __syncthreads();

    if (tid < nsb) {
      const int h = dlist[sb + tid];
      const float mywr = wrec[h];
      float V = 0.f, Sv = 0.f, cnt = 0.f;
#pragma unroll 1
      for (int tt = 0; tt < T_LEN; ++tt) {
        float xv = xcol[tid][tt];
        V = 0.9f * V + xv + mywr * Sv;
        float sn = (V - 1.0f > 0.0f) ? 1.0f : 0.0f;
        V -= sn;
        cnt += sn;
        Sv = sn;
        spkb[tid][tt] = (unsigned char)sn;
      }
      scnt[b * HID + h] = cnt;
    }
    __syncthreads();

    for (int p = tid; p < T_LEN * 8; p += 512) {
      int tt = p >> 3, wv = p & 7;
      uint32_t mc = 0, ms = 0;
      for (int j = 0; j < nsb; ++j) {
        int h = dlist[sb + j];
        if ((h >> 5) == wv) {
          uint32_t bit = 1u << (h & 31);
          mc |= bit;
          if (spkb[j][tt]) ms |= bit;
        }
      }
      if (mc) {
        size_t w = ((size_t)tt * B_SZ + b) * 8 + wv;
        sbits[w] = (sbits[w] & ~mc) | ms;
      }
    }
    __syncthreads();
  }
}

// ---------------- K3: logits = spikes @ W_head + b_head (r12-proven) -------
#define LDA 40
__global__ __launch_bounds__(256) void k3_logits(
    const uint32_t* __restrict__ sbits, const _Float16* __restrict__ Wh3,
    const float* __restrict__ bhead, float* __restrict__ logits)
{
  __shared__ __align__(16) _Float16 Sa[128][LDA];
  __shared__ __align__(16) _Float16 Wt[128][LDA];

  const int tid  = threadIdx.x;
  const int brow = blockIdx.x * 128;
  const int srow = tid >> 1, sks = (tid & 1) << 4;
  const int wid = tid >> 6, lane = tid & 63;
  const int wr = wid >> 1, wc = wid & 1;
  const int fr = lane & 15, fq = lane >> 4;

  f32x4 acc[4][4] = {};
  uint32_t wbits;
  uint4 wb0, wb1;

  auto loadS = [&](int c) { wbits = sbits[(size_t)(brow + srow) * 8 + c]; };
  auto loadW = [&](int c) {
    const _Float16* p = Wh3 + ((size_t)c * 128 + srow) * 32 + sks;
    wb0 = *reinterpret_cast<const uint4*>(p);
    wb1 = *reinterpret_cast<const uint4*>(p + 8);
  };

  loadS(0); loadW(0);

  for (int c = 0; c < 8; ++c) {
    __syncthreads();
    {
      f16x8 e0, e1;
#pragma unroll
      for (int j = 0; j < 8; ++j) {
        e0[j] = (_Float16)(float)((wbits >> (sks + j)) & 1u);
        e1[j] = (_Float16)(float)((wbits >> (sks + 8 + j)) & 1u);
      }
      *reinterpret_cast<f16x8*>(&Sa[srow][sks])     = e0;
      *reinterpret_cast<f16x8*>(&Sa[srow][sks + 8]) = e1;
    }
    *reinterpret_cast<uint4*>(&Wt[srow][sks])     = wb0;
    *reinterpret_cast<uint4*>(&Wt[srow][sks + 8]) = wb1;
    __syncthreads();
    if (c + 1 < 8) { loadS(c + 1); loadW(c + 1); }

    f16x8 wf[4];
#pragma unroll
    for (int nf = 0; nf < 4; ++nf)
      wf[nf] = *reinterpret_cast<const f16x8*>(&Wt[wc * 64 + nf * 16 + fr][fq * 8]);
#pragma unroll
    for (int mf = 0; mf < 4; ++mf) {
      f16x8 sf = *reinterpret_cast<const f16x8*>(&Sa[wr * 64 + mf * 16 + fr][fq * 8]);
#pragma unroll
      for (int nf = 0; nf < 4; ++nf)
        acc[mf][nf] = __builtin_amdgcn_mfma_f32_16x16x32_f16(sf, wf[nf], acc[mf][nf], 0, 0, 0);
    }
  }

#pragma unroll
  for (int mf = 0; mf < 4; ++mf)
#pragma unroll
    for (int nf = 0; nf < 4; ++nf) {
      int n = wc * 64 + nf * 16 + fr;
      float bv = bhead[n];
#pragma unroll
      for (int r = 0; r < 4; ++r) {
        int m = brow + wr * 64 + mf * 16 + fq * 4 + r;
        logits[(size_t)m * OUT + n] = acc[mf][nf][r] + bv;
      }
    }
}

// ---------------- K4: out = (spike_counts / T) @ W_head + b_head (fp32) ----
__global__ __launch_bounds__(128) void k4_out(
    const float* __restrict__ scnt, const float* __restrict__ Whead,
    const float* __restrict__ bhead, float* __restrict__ outp)
{
  __shared__ float s[HID];
  const int b = blockIdx.x;
  const int o = threadIdx.x;
  s[o] = scnt[b * HID + o];
  s[o + 128] = scnt[b * HID + o + 128];
  __syncthreads();
  float acc = 0.f;
#pragma unroll 8
  for (int h = 0; h < HID; ++h) acc += s[h] * Whead[h * OUT + o];
  outp[b * OUT + o] = acc * (1.0f / (float)T_LEN) + bhead[o];
}

extern "C" void kernel_launch(void* const* d_in, const int* in_sizes, int n_in,
                              void* d_out, int out_size, void* d_ws, size_t ws_size,
                              hipStream_t stream)
{
  const float* vis   = (const float*)d_in[0];
  const float* imu   = (const float*)d_in[1];
  const float* traj  = (const float*)d_in[2];
  const float* Win   = (const float*)d_in[3];
  const float* bin   = (const float*)d_in[4];
  const float* wrec  = (const float*)d_in[5];
  const float* Whead = (const float*)d_in[6];
  const float* bhead = (const float*)d_in[7];

  float* outp   = (float*)d_out;           // [B, OUT] (return order: out, logits)
  float* logits = outp + B_SZ * OUT;       // [T, B, OUT]

  char* ws = (char*)d_ws;
  const size_t SBITS_B = (size_t)MROWS * 8 * 4;        // 4.19 MB
  const size_t SCNT_B  = (size_t)B_SZ * HID * 4;       // 256 KB
  const size_t BPACK_B = (size_t)24 * 8192 * 2;        // 384 KB
  uint32_t* sbits = (uint32_t*)ws;
  float*    scnt  = (float*)(ws + SBITS_B);
  _Float16* Bpack = (_Float16*)(ws + SBITS_B + SCNT_B);
  _Float16* Wh3   = (_Float16*)(ws + SBITS_B + SCNT_B + BPACK_B);

  prep_all  <<<dim3(224),         256, 0, stream>>>(Win, Whead, Bpack, Wh3);
  k12_fused <<<dim3(512),         512, 0, stream>>>(vis, imu, traj, Bpack, bin,
                                                    wrec, sbits, scnt);
  k2_fix    <<<dim3(B_SZ),        512, 0, stream>>>(vis, imu, traj, Win, bin,
                                                    wrec, sbits, scnt);
  k3_logits <<<dim3(MROWS / 128), 256, 0, stream>>>(sbits, Wh3, bhead, logits);
  k4_out    <<<dim3(B_SZ),        128, 0, stream>>>(scnt, Whead, bhead, outp);
}

// Round 23
// 258.252 us; speedup vs baseline: 1.4574x; 1.2315x over previous
//
#include <hip/hip_runtime.h>
#include <hip/hip_bf16.h>
#include <cstdint>

#define T_LEN 512
#define B_SZ  256
#define HID   256
#define OUT   128
#define FUSE  384
#define MROWS (T_LEN * B_SZ)   // 131072
#define FT    64               // t-chunk of the fused kernel

typedef _Float16 f16x8 __attribute__((ext_vector_type(8)));
typedef float f32x4 __attribute__((ext_vector_type(4)));

// fp16x2 split of (2^12 * a): a' = h + l*2^-11.  x = (acc_hh + acc_hl*2^-11)*2^-24.
#define PRESC 4096.0f
#define S1    2048.0f
#define S1INV 4.8828125e-4f             // 2^-11
#define C0    5.9604644775390625e-8f    // 2^-24

// V-margin below which a neuron is recomputed with the exact fp32 chain.
#define EPSV  5e-5f

// Raw barriers (no vmcnt drain): private register prefetch loads stay in
// flight across the barrier; only LDS ordering is enforced.
__device__ __forceinline__ void bar_plain() {
  asm volatile("s_barrier" ::: "memory");
}
__device__ __forceinline__ void bar_lds() {
  asm volatile("s_waitcnt lgkmcnt(0)\n\ts_barrier" ::: "memory");
}

// ---------------- prep (merged): W_in fp16x2 images + W_head fp16 ----------
__global__ __launch_bounds__(256) void prep_all(const float* __restrict__ Win,
                                                const float* __restrict__ Wh,
                                                _Float16* __restrict__ Bpack,
                                                _Float16* __restrict__ Wh3)
{
  int gid = blockIdx.x;
  if (gid < 96) {
    int id = gid * 256 + threadIdx.x;          // 24576 = 24 images x 1024 slots
    int img = id >> 10;                        // c*2 + bc
    int c = img >> 1, bc = img & 1;
    int slot = id & 1023;
    int s = slot >> 9, sub = (slot >> 6) & 7, pos = slot & 63;
    int fr = pos & 15, fq = pos >> 4;          // pos = fq*16 + fr
    int n = bc * 128 + sub * 16 + fr;
    int k0 = c * 32 + fq * 8;
    f16x8 v;
#pragma unroll
    for (int j = 0; j < 8; ++j) {
      float w = Win[(size_t)(k0 + j) * HID + n] * PRESC;
      _Float16 h = (_Float16)w;
      v[j] = (s == 0) ? h : (_Float16)((w - (float)h) * S1);
    }
    *reinterpret_cast<f16x8*>(&Bpack[(size_t)img * 8192 + slot * 8]) = v;
  } else {
    int id = (gid - 96) * 256 + threadIdx.x;   // 32768
    int n = id & 127, kk = (id >> 7) & 31, c = id >> 12;
    Wh3[((size_t)c * 128 + n) * 32 + kk] = (_Float16)Wh[(c * 32 + kk) * OUT + n];
  }
}

// ---------------- K12: FUSED GEMM + scan (raw barriers + 2-deep A prefetch)
// Block = (b, h-half). c-loop manually paired (even/odd bodies) with two
// NAMED A-register sets (aE*, aO*) so each A load is issued TWO intervals
// before its consuming conversion — with raw barriers (no vmcnt drain) the
// loads genuinely stay in flight across two barrier pairs. Staging/MFMA
// arithmetic identical to r12 -> bit-identical output. (512,4): VGPR 64,
// no spill, 2 blocks/CU — measured best (k12 ~163us, total 258us).
__global__ __launch_bounds__(512, 4) void k12_fused(
    const float* __restrict__ vis, const float* __restrict__ imu,
    const float* __restrict__ traj, const _Float16* __restrict__ Bpack,
    const float* __restrict__ bin, const float* __restrict__ wrec,
    uint32_t* __restrict__ sbits, float* __restrict__ scnt)
{
  __shared__ __align__(16) _Float16 Asl[4096];   // [s2][sub4][pos64][j8] 8KB
  __shared__ float xt[FT][130];                  // 33.3KB; 2 lanes/bank (free)

  const int bid = blockIdx.x;
  const int b   = bid & 255;
  const int hh  = bid >> 8;                 // h-half 0/1
  const int tid = threadIdx.x;
  const int wid = tid >> 6, lane = tid & 63;
  const int wr = wid >> 2, wc = wid & 3;    // 2M(t) x 4N(h)
  const int fr = lane & 15, fq = lane >> 4;

  // A staging coords (threads 0..255 stage 8 floats = one j8 slot each)
  const int arow = tid >> 2;                // 0..63 (tid<256)
  const int ak   = (tid & 3) * 8;           // k-offset {0,8,16,24}
  const int asub = arow >> 4;
  const int apos = (tid & 3) * 16 + (arow & 15);   // pos = fq*16+fr

  // scan state (threads 0..127: h_local = tid)
  float V = 0.f, S = 0.f, cnt = 0.f, minm = 1e9f;
  const float wrv = (tid < 128) ? wrec[hh * 128 + tid] : 0.f;
  float bvv[2];
  bvv[0] = bin[hh * 128 + wc * 32 + fr];
  bvv[1] = bin[hh * 128 + wc * 32 + 16 + fr];

  float4 aE0, aE1, aO0, aO1;                // two named A prefetch sets
  f16x8 pb0, pb1, pb2, pb3;                 // B prefetch (bh0,bh1,bl0,bl1)

  auto loadA = [&](int cc, float4& d0, float4& d1) {   // cc = linear chunk
    if (tid < 256 && cc < 96) {
      int tcc = cc / 12, c = cc - tcc * 12;
      size_t m = (size_t)(tcc * FT + arow) * B_SZ + b;
      const float* src; size_t off;
      if (c < 8)       { src = vis;  off = m * 256 + c * 32 + ak; }
      else if (c < 10) { src = imu;  off = m * 64 + (c - 8) * 32 + ak; }
      else             { src = traj; off = m * 64 + (c - 10) * 32 + ak; }
      d0 = *reinterpret_cast<const float4*>(src + off);
      d1 = *reinterpret_cast<const float4*>(src + off + 4);
    }
  };
  auto loadB = [&](int cc) {
    if (cc < 96) {
      int c = cc - (cc / 12) * 12;
      const _Float16* base = Bpack + (size_t)(c * 2 + hh) * 8192;
      pb0 = *reinterpret_cast<const f16x8*>(base + (wc * 2 + 0) * 512 + lane * 8);
      pb1 = *reinterpret_cast<const f16x8*>(base + (wc * 2 + 1) * 512 + lane * 8);
      pb2 = *reinterpret_cast<const f16x8*>(base + 4096 + (wc * 2 + 0) * 512 + lane * 8);
      pb3 = *reinterpret_cast<const f16x8*>(base + 4096 + (wc * 2 + 1) * 512 + lane * 8);
    }
  };

  auto stage = [&](const float4& s0, const float4& s1) {
    if (tid < 256) {
      float av[8] = {s0.x, s0.y, s0.z, s0.w, s1.x, s1.y, s1.z, s1.w};
      f16x8 vh, vl;
#pragma unroll
      for (int j = 0; j < 8; ++j) {
        float w = av[j] * PRESC;
        _Float16 h = (_Float16)w;
        vh[j] = h;
        vl[j] = (_Float16)((w - (float)h) * S1);
      }
      *reinterpret_cast<f16x8*>(&Asl[asub * 512 + apos * 8])        = vh;
      *reinterpret_cast<f16x8*>(&Asl[2048 + asub * 512 + apos * 8]) = vl;
    }
  };

  loadA(0, aE0, aE1);
  loadA(1, aO0, aO1);
  loadB(0);

  for (int tc = 0; tc < 8; ++tc) {
    f32x4 acc0[2][2] = {};   // hh
    f32x4 acc1[2][2] = {};   // hl + lh  (x 2^-11)

#pragma unroll 1
    for (int i = 0; i < 6; ++i) {
      const int ccE = tc * 12 + 2 * i;

      // ---------- even chunk ----------
      bar_plain();                         // Asl free (reads in regs already)
      stage(aE0, aE1);
      loadA(ccE + 2, aE0, aE1);            // 2-deep: in flight across 2 pairs
      bar_lds();                           // ds_writes visible
      {
        f16x8 bh_0 = pb0, bh_1 = pb1, bl_0 = pb2, bl_1 = pb3;
        loadB(ccE + 1);
#pragma unroll
        for (int mf = 0; mf < 2; ++mf) {
          int sa = wr * 2 + mf;
          f16x8 ah = *reinterpret_cast<const f16x8*>(&Asl[sa * 512 + lane * 8]);
          f16x8 al = *reinterpret_cast<const f16x8*>(&Asl[2048 + sa * 512 + lane * 8]);
          acc0[mf][0] = __builtin_amdgcn_mfma_f32_16x16x32_f16(ah, bh_0, acc0[mf][0], 0, 0, 0);
          acc1[mf][0] = __builtin_amdgcn_mfma_f32_16x16x32_f16(ah, bl_0, acc1[mf][0], 0, 0, 0);
          acc1[mf][0] = __builtin_amdgcn_mfma_f32_16x16x32_f16(al, bh_0, acc1[mf][0], 0, 0, 0);
          acc0[mf][1] = __builtin_amdgcn_mfma_f32_16x16x32_f16(ah, bh_1, acc0[mf][1], 0, 0, 0);
          acc1[mf][1] = __builtin_amdgcn_mfma_f32_16x16x32_f16(ah, bl_1, acc1[mf][1], 0, 0, 0);
          acc1[mf][1] = __builtin_amdgcn_mfma_f32_16x16x32_f16(al, bh_1, acc1[mf][1], 0, 0, 0);
        }
      }

      // ---------- odd chunk ----------
      bar_plain();
      stage(aO0, aO1);
      loadA(ccE + 3, aO0, aO1);
      bar_lds();
      {
        f16x8 bh_0 = pb0, bh_1 = pb1, bl_0 = pb2, bl_1 = pb3;
        loadB(ccE + 2);
#pragma unroll
        for (int mf = 0; mf < 2; ++mf) {
          int sa = wr * 2 + mf;
          f16x8 ah = *reinterpret_cast<const f16x8*>(&Asl[sa * 512 + lane * 8]);
          f16x8 al = *reinterpret_cast<const f16x8*>(&Asl[2048 + sa * 512 + lane * 8]);
          acc0[mf][0] = __builtin_amdgcn_mfma_f32_16x16x32_f16(ah, bh_0, acc0[mf][0], 0, 0, 0);
          acc1[mf][0] = __builtin_amdgcn_mfma_f32_16x16x32_f16(ah, bl_0, acc1[mf][0], 0, 0, 0);
          acc1[mf][0] = __builtin_amdgcn_mfma_f32_16x16x32_f16(al, bh_0, acc1[mf][0], 0, 0, 0);
          acc0[mf][1] = __builtin_amdgcn_mfma_f32_16x16x32_f16(ah, bh_1, acc0[mf][1], 0, 0, 0);
          acc1[mf][1] = __builtin_amdgcn_mfma_f32_16x16x32_f16(ah, bl_1, acc1[mf][1], 0, 0, 0);
          acc1[mf][1] = __builtin_amdgcn_mfma_f32_16x16x32_f16(al, bh_1, acc1[mf][1], 0, 0, 0);
        }
      }
    }

    // epilogue: x-tile to LDS (full __syncthreads handoffs; 2 per tc only)
    __syncthreads();
#pragma unroll
    for (int mf = 0; mf < 2; ++mf)
#pragma unroll
      for (int nf = 0; nf < 2; ++nf) {
        int col = wc * 32 + nf * 16 + fr;
        int rbase = wr * 32 + mf * 16 + fq * 4;
#pragma unroll
        for (int r = 0; r < 4; ++r)
          xt[rbase + r][col] =
              (acc0[mf][nf][r] + acc1[mf][nf][r] * S1INV) * C0 + bvv[nf];
      }
    __syncthreads();                       // x-tile ready for scan

    // scan: threads 0..127 (waves 0,1), arithmetic = proven k2_scan verbatim
    if (tid < 128) {
#pragma unroll 1
      for (int u0 = 0; u0 < FT; u0 += 8) {
        float xv[8];
#pragma unroll
        for (int u = 0; u < 8; ++u) xv[u] = xt[u0 + u][tid];
#pragma unroll
        for (int u = 0; u < 8; ++u) {
          V = 0.9f * V + xv[u] + wrv * S;
          float d = V - 1.0f;
          float sn = (d > 0.0f) ? 1.0f : 0.0f;
          minm = fminf(minm, fabsf(d));
          V -= sn;
          cnt += sn;
          S = sn;
          unsigned long long mk = __ballot(sn > 0.5f);
          if (lane == 0) {
            int m = (tc * FT + u0 + u) * B_SZ + b;
            int wv = hh * 2 + wid;
            sbits[(size_t)m * 8 + wv * 2 + 0] = (uint32_t)(mk & 0xffffffffull);
            sbits[(size_t)m * 8 + wv * 2 + 1] = (uint32_t)(mk >> 32);
          }
        }
      }
    }
    // next tc's first bar_plain orders scan xt-reads vs. future xt writes
  }

  if (tid < 128)
    scnt[b * HID + hh * 128 + tid] = (minm < EPSV) ? (-cnt - 1.0f) : cnt;
}

// ---------------- K2_fix: 512 thr, 1 t/thread, FSL=12, 4-deep prefetch -----
#define FSL 12
__global__ __launch_bounds__(512) void k2_fix(
    const float* __restrict__ vis, const float* __restrict__ imu,
    const float* __restrict__ traj, const float* __restrict__ Win,
    const float* __restrict__ bin, const float* __restrict__ wrec,
    uint32_t* __restrict__ sbits, float* __restrict__ scnt)
{
  __shared__ __align__(16) float Wlds[FSL][392];   // 16B-aligned rows
  __shared__ float xcol[FSL][521];
  __shared__ unsigned char spkb[FSL][516];
  __shared__ int dlist[256];
  __shared__ int nd;

  const int b = blockIdx.x;
  const int tid = threadIdx.x;
  if (tid == 0) nd = 0;
  __syncthreads();
  if (tid < 256) {
    if (scnt[b * HID + tid] < -0.5f) {
      int p = atomicAdd(&nd, 1);
      dlist[p] = tid;
    }
  }
  __syncthreads();
  const int nd0 = nd;
  if (nd0 == 0) return;

  const int t = tid;
  const size_t r = (size_t)t * B_SZ + b;

  for (int sb = 0; sb < nd0; sb += FSL) {
    const int nsb = min(FSL, nd0 - sb);

    for (int idx = tid; idx < FSL * 384; idx += 512) {
      int s = idx / 384, k = idx - s * 384;
      float w = 0.f;
      if (s < nsb) w = Win[(size_t)k * HID + dlist[sb + s]];
      Wlds[s][k] = w;
    }
    __syncthreads();

    float x[FSL];
#pragma unroll
    for (int s = 0; s < FSL; ++s) x[s] = 0.f;

#define SEG(SRC, LEN, DIM, WOFS)                                              \
    {                                                                         \
      const float* src = SRC + r * DIM;                                       \
      _Pragma("unroll 1")                                                     \
      for (int q = 0; q < LEN; q += 4) {                                      \
        float4 a0 = *reinterpret_cast<const float4*>(src + q * 4);            \
        float4 a1 = *reinterpret_cast<const float4*>(src + q * 4 + 4);        \
        float4 a2 = *reinterpret_cast<const float4*>(src + q * 4 + 8);        \
        float4 a3 = *reinterpret_cast<const float4*>(src + q * 4 + 12);       \
        _Pragma("unroll")                                                     \
        for (int s = 0; s < FSL; ++s) {                                       \
          float4 w = *reinterpret_cast<const float4*>(&Wlds[s][WOFS + q * 4]);\
          x[s] += a0.x * w.x; x[s] += a0.y * w.y;                             \
          x[s] += a0.z * w.z; x[s] += a0.w * w.w;                             \
        }                                                                     \
        _Pragma("unroll")                                                     \
        for (int s = 0; s < FSL; ++s) {                                       \
          float4 w = *reinterpret_cast<const float4*>(&Wlds[s][WOFS + q * 4 + 4]); \
          x[s] += a1.x * w.x; x[s] += a1.y * w.y;                             \
          x[s] += a1.z * w.z; x[s] += a1.w * w.w;                             \
        }                                                                     \
        _Pragma("unroll")                                                     \
        for (int s = 0; s < FSL; ++s) {                                       \
          float4 w = *reinterpret_cast<const float4*>(&Wlds[s][WOFS + q * 4 + 8]); \
          x[s] += a2.x * w.x; x[s] += a2.y * w.y;                             \
          x[s] += a2.z * w.z; x[s] += a2.w * w.w;                             \
        }                                                                     \
        _Pragma("unroll")                                                     \
        for (int s = 0; s < FSL; ++s) {                                       \
          float4 w = *reinterpret_cast<const float4*>(&Wlds[s][WOFS + q * 4 + 12]); \
          x[s] += a3.x * w.x; x[s] += a3.y * w.y;                             \
          x[s] += a3.z * w.z; x[s] += a3.w * w.w;                             \
        }                                                                     \
      }                                                                       \
    }

    SEG(vis,  64, 256, 0)
    SEG(imu,  16, 64,  256)
    SEG(traj, 16, 64,  320)
#undef SEG

#pragma unroll
    for (int s = 0; s < FSL; ++s) {
      if (s < nsb) xcol[s][t] = x[s] + bin[dlist[sb + s]];
    }
    __syncthreads();

    if (tid < nsb) {
      const int h = dlist[sb + tid];
      const float mywr = wrec[h];
      float V = 0.f, Sv = 0.f, cnt = 0.f;
#pragma unroll 1
      for (int tt = 0; tt < T_LEN; ++tt) {
        float xv = xcol[tid][tt];
        V = 0.9f * V + xv + mywr * Sv;
        float sn = (V - 1.0f > 0.0f) ? 1.0f : 0.0f;
        V -= sn;
        cnt += sn;
        Sv = sn;
        spkb[tid][tt] = (unsigned char)sn;
      }
      scnt[b * HID + h] = cnt;
    }
    __syncthreads();

    for (int p = tid; p < T_LEN * 8; p += 512) {
      int tt = p >> 3, wv = p & 7;
      uint32_t mc = 0, ms = 0;
      for (int j = 0; j < nsb; ++j) {
        int h = dlist[sb + j];
        if ((h >> 5) == wv) {
          uint32_t bit = 1u << (h & 31);
          mc |= bit;
          if (spkb[j][tt]) ms |= bit;
        }
      }
      if (mc) {
        size_t w = ((size_t)tt * B_SZ + b) * 8 + wv;
        sbits[w] = (sbits[w] & ~mc) | ms;
      }
    }
    __syncthreads();
  }
}

// ---------------- K3: logits = spikes @ W_head + b_head (r12-proven) -------
#define LDA 40
__global__ __launch_bounds__(256) void k3_logits(
    const uint32_t* __restrict__ sbits, const _Float16* __restrict__ Wh3,
    const float* __restrict__ bhead, float* __restrict__ logits)
{
  __shared__ __align__(16) _Float16 Sa[128][LDA];
  __shared__ __align__(16) _Float16 Wt[128][LDA];

  const int tid  = threadIdx.x;
  const int brow = blockIdx.x * 128;
  const int srow = tid >> 1, sks = (tid & 1) << 4;
  const int wid = tid >> 6, lane = tid & 63;
  const int wr = wid >> 1, wc = wid & 1;
  const int fr = lane & 15, fq = lane >> 4;

  f32x4 acc[4][4] = {};
  uint32_t wbits;
  uint4 wb0, wb1;

  auto loadS = [&](int c) { wbits = sbits[(size_t)(brow + srow) * 8 + c]; };
  auto loadW = [&](int c) {
    const _Float16* p = Wh3 + ((size_t)c * 128 + srow) * 32 + sks;
    wb0 = *reinterpret_cast<const uint4*>(p);
    wb1 = *reinterpret_cast<const uint4*>(p + 8);
  };

  loadS(0); loadW(0);

  for (int c = 0; c < 8; ++c) {
    __syncthreads();
    {
      f16x8 e0, e1;
#pragma unroll
      for (int j = 0; j < 8; ++j) {
        e0[j] = (_Float16)(float)((wbits >> (sks + j)) & 1u);
        e1[j] = (_Float16)(float)((wbits >> (sks + 8 + j)) & 1u);
      }
      *reinterpret_cast<f16x8*>(&Sa[srow][sks])     = e0;
      *reinterpret_cast<f16x8*>(&Sa[srow][sks + 8]) = e1;
    }
    *reinterpret_cast<uint4*>(&Wt[srow][sks])     = wb0;
    *reinterpret_cast<uint4*>(&Wt[srow][sks + 8]) = wb1;
    __syncthreads();
    if (c + 1 < 8) { loadS(c + 1); loadW(c + 1); }

    f16x8 wf[4];
#pragma unroll
    for (int nf = 0; nf < 4; ++nf)
      wf[nf] = *reinterpret_cast<const f16x8*>(&Wt[wc * 64 + nf * 16 + fr][fq * 8]);
#pragma unroll
    for (int mf = 0; mf < 4; ++mf) {
      f16x8 sf = *reinterpret_cast<const f16x8*>(&Sa[wr * 64 + mf * 16 + fr][fq * 8]);
#pragma unroll
      for (int nf = 0; nf < 4; ++nf)
        acc[mf][nf] = __builtin_amdgcn_mfma_f32_16x16x32_f16(sf, wf[nf], acc[mf][nf], 0, 0, 0);
    }
  }

#pragma unroll
  for (int mf = 0; mf < 4; ++mf)
#pragma unroll
    for (int nf = 0; nf < 4; ++nf) {
      int n = wc * 64 + nf * 16 + fr;
      float bv = bhead[n];
#pragma unroll
      for (int r = 0; r < 4; ++r) {
        int m = brow + wr * 64 + mf * 16 + fq * 4 + r;
        logits[(size_t)m * OUT + n] = acc[mf][nf][r] + bv;
      }
    }
}

// ---------------- K4: out = (spike_counts / T) @ W_head + b_head (fp32) ----
__global__ __launch_bounds__(128) void k4_out(
    const float* __restrict__ scnt, const float* __restrict__ Whead,
    const float* __restrict__ bhead, float* __restrict__ outp)
{
  __shared__ float s[HID];
  const int b = blockIdx.x;
  const int o = threadIdx.x;
  s[o] = scnt[b * HID + o];
  s[o + 128] = scnt[b * HID + o + 128];
  __syncthreads();
  float acc = 0.f;
#pragma unroll 8
  for (int h = 0; h < HID; ++h) acc += s[h] * Whead[h * OUT + o];
  outp[b * OUT + o] = acc * (1.0f / (float)T_LEN) + bhead[o];
}

extern "C" void kernel_launch(void* const* d_in, const int* in_sizes, int n_in,
                              void* d_out, int out_size, void* d_ws, size_t ws_size,
                              hipStream_t stream)
{
  const float* vis   = (const float*)d_in[0];
  const float* imu   = (const float*)d_in[1];
  const float* traj  = (const float*)d_in[2];
  const float* Win   = (const float*)d_in[3];
  const float* bin   = (const float*)d_in[4];
  const float* wrec  = (const float*)d_in[5];
  const float* Whead = (const float*)d_in[6];
  const float* bhead = (const float*)d_in[7];

  float* outp   = (float*)d_out;           // [B, OUT] (return order: out, logits)
  float* logits = outp + B_SZ * OUT;       // [T, B, OUT]

  char* ws = (char*)d_ws;
  const size_t SBITS_B = (size_t)MROWS * 8 * 4;        // 4.19 MB
  const size_t SCNT_B  = (size_t)B_SZ * HID * 4;       // 256 KB
  const size_t BPACK_B = (size_t)24 * 8192 * 2;        // 384 KB
  uint32_t* sbits = (uint32_t*)ws;
  float*    scnt  = (float*)(ws + SBITS_B);
  _Float16* Bpack = (_Float16*)(ws + SBITS_B + SCNT_B);
  _Float16* Wh3   = (_Float16*)(ws + SBITS_B + SCNT_B + BPACK_B);

  prep_all  <<<dim3(224),         256, 0, stream>>>(Win, Whead, Bpack, Wh3);
  k12_fused <<<dim3(512),         512, 0, stream>>>(vis, imu, traj, Bpack, bin,
                                                    wrec, sbits, scnt);
  k2_fix    <<<dim3(B_SZ),        512, 0, stream>>>(vis, imu, traj, Win, bin,
                                                    wrec, sbits, scnt);
  k3_logits <<<dim3(MROWS / 128), 256, 0, stream>>>(sbits, Wh3, bhead, logits);
  k4_out    <<<dim3(B_SZ),        128, 0, stream>>>(scnt, Whead, bhead, outp);
}